// Round 6
// baseline (381.241 us; speedup 1.0000x reference)
//
#include <hip/hip_runtime.h>
#include <stdint.h>

#define NR 8192
#define DE 1024
#define DC 512
#define BIGF 9999999.0f
#define MARG 0.3f
#define NEGI -3.0e38f
#define POSI 3.0e38f
#define CAPR 48   // class rows staged in LDS (max class ~32 for this input; >CAPR falls back to global)

typedef __attribute__((ext_vector_type(8))) short bf16x8;
typedef __attribute__((ext_vector_type(4))) float f32x4;

typedef __attribute__((address_space(3))) unsigned int lds_u32;
typedef const __attribute__((address_space(1))) unsigned int glb_u32;

static __device__ __forceinline__ void ld_g2l16(const void* g, void* l) {
    __builtin_amdgcn_global_load_lds((glb_u32*)g, (lds_u32*)l, 16, 0, 0);
}

static __device__ __forceinline__ unsigned short f2bf(float x) {
    unsigned u = __float_as_uint(x);
    unsigned r = u + 0x7FFFu + ((u >> 16) & 1u);
    return (unsigned short)(r >> 16);
}

static __device__ __forceinline__ float b2f(short u) {
    return __uint_as_float(((unsigned)(unsigned short)u) << 16);
}

// ---------------- K1: emb -> bf16, sq[i] = ||emb_i||^2, class histogram ----------------
__global__ __launch_bounds__(256) void k_prep_emb(const float* __restrict__ emb,
                                                  const int* __restrict__ label,
                                                  short* __restrict__ embb,
                                                  float* __restrict__ sq,
                                                  int* __restrict__ cnt) {
    int row = blockIdx.x, tid = threadIdx.x;
    float4 v = ((const float4*)(emb + (size_t)row * DE))[tid];
    float s = v.x * v.x + v.y * v.y + v.z * v.z + v.w * v.w;
    ushort4 b;
    b.x = f2bf(v.x); b.y = f2bf(v.y); b.z = f2bf(v.z); b.w = f2bf(v.w);
    *(ushort4*)&embb[(size_t)row * DE + tid * 4] = b;
    for (int m = 1; m < 64; m <<= 1) s += __shfl_xor(s, m);
    __shared__ float red[4];
    if ((tid & 63) == 0) red[tid >> 6] = s;
    __syncthreads();
    if (tid == 0) {
        sq[row] = red[0] + red[1] + red[2] + red[3];
        atomicAdd(&cnt[label[row]], 1);
    }
}

// ---------------- K2: exclusive scan of class counts (512, single block) ----------------
__global__ __launch_bounds__(512) void k_scan(const int* __restrict__ cnt,
                                              int* __restrict__ clsOff) {
    __shared__ int s[512];
    int t = threadIdx.x;
    s[t] = cnt[t];
    __syncthreads();
    for (int d = 1; d < 512; d <<= 1) {
        int v = (t >= d) ? s[t - d] : 0;
        __syncthreads();
        s[t] += v;
        __syncthreads();
    }
    clsOff[t] = s[t] - cnt[t];
}

// ---------------- K3: scatter rows into class member lists ----------------
__global__ __launch_bounds__(256) void k_fill(const int* __restrict__ label,
                                              const int* __restrict__ clsOff,
                                              int* __restrict__ fill,
                                              int* __restrict__ list) {
    int i = blockIdx.x * 256 + threadIdx.x;
    int l = label[i];
    int p = atomicAdd(&fill[l], 1);
    list[clsOff[l] + p] = i;
}

// ---------------- K4: symmetric GEMM + min-of-negative row & column reductions ----------------
// ROUND-6 DELTA vs the proven round-0 skeleton (unchanged: 2-barrier K-step, gload_lds
// staging + source swizzle, pxor fragment swizzle, 16KB LDS, launch_bounds(256,3)):
//  (1) per-PANEL grid: 2080 blocks, one 128x128 upper-tri panel each (r<=c<64), 32 K-steps.
//      Fixes the measured residency imbalance of the 544-block grid (544 = 2*256+32 -> 32
//      CUs carried 3 concurrent full blocks = 1.48x the average work; wall = hot-CU time,
//      invariant to all in-block scheduling -- matches R0/R1/R2/R5 null results). 2080
//      blocks at 3/CU refill dynamically; tail imbalance ~6%.
//  (2) 2x2 wave arrangement, 64x64 output per wave (acc[4][4], af[4]+bfr[4] = 8 ds_reads
//      vs 10): B-tile read-duplication 4x -> 2x; LDS traffic per block-K-step 56->48KB
//      (LDS pipe was the busiest: ~72 B/cyc of the ~85 B/cyc b128 ceiling on hot CUs).
//  Row/col coverage per panel: row-side covers x-in-r vs y-in-c, col-side y-in-c vs x-in-r;
//  diagonal panels double-count pairs (harmless for min); self masked by label equality.
__global__ __launch_bounds__(256, 3) void k_main(const short* __restrict__ embb,
                                                 const float* __restrict__ sq,
                                                 const int* __restrict__ label,
                                                 unsigned* __restrict__ mnA) {
    // decode b -> (r, c), r <= c < 64, row-major upper triangle incl diagonal:
    // off(r) = 64r - r(r-1)/2 ; c = r + (b - off(r))
    const int b = blockIdx.x;
    int r = (int)((129.0f - sqrtf(16641.0f - 8.0f * (float)b)) * 0.5f);
    if (r < 0) r = 0;
    if (r > 63) r = 63;
    while (r > 0 && 64 * r - (r * (r - 1)) / 2 > b) --r;
    while (64 * (r + 1) - ((r + 1) * r) / 2 <= b) ++r;
    const int c = r + (b - (64 * r - (r * (r - 1)) / 2));
    const int i0 = r * 128, j0 = c * 128;

    __shared__ __align__(16) short As[128 * 32];
    __shared__ __align__(16) short Bs[128 * 32];

    const int tid = threadIdx.x;
    const int lane = tid & 63;
    const int w = tid >> 6;
    const int wr = w >> 1, wc = w & 1;       // 2x2 wave grid over the 128x128 panel
    const int q = lane >> 4, l15 = lane & 15;

    // staging source swizzle: slot rr = tid>>2, c = tid&3 -> global chunk g (verbatim R0)
    const int srow = tid >> 2;
    const int g = (tid & 3) ^ ((tid >> 3) & 3);
    const short* gA = embb + (size_t)(i0 + srow) * DE + g * 8;
    const short* gB = embb + (size_t)(j0 + srow) * DE + g * 8;

    // fragment read swizzle (conflict-free; valid for any 16-aligned row base)
    const int pxor = q ^ ((l15 >> 1) & 3);

    auto stage = [&](int koff) {
        ld_g2l16(gA + koff, &As[(size_t)tid * 8]);
        ld_g2l16(gA + (size_t)64 * DE + koff, &As[(size_t)(tid + 256) * 8]);
        ld_g2l16(gB + koff, &Bs[(size_t)tid * 8]);
        ld_g2l16(gB + (size_t)64 * DE + koff, &Bs[(size_t)(tid + 256) * 8]);
    };

    stage(0);   // prefetch ks=0

    f32x4 acc[4][4];
#pragma unroll
    for (int mi = 0; mi < 4; ++mi)
#pragma unroll
        for (int ni = 0; ni < 4; ++ni) acc[mi][ni] = (f32x4){0.f, 0.f, 0.f, 0.f};

    for (int ks = 0; ks < 32; ++ks) {
        __syncthreads();          // staging visible (vmcnt drain)
        bf16x8 af[4], bfr[4];
#pragma unroll
        for (int mi = 0; mi < 4; ++mi)
            af[mi] = *(const bf16x8*)&As[(wr * 64 + mi * 16 + l15) * 32 + pxor * 8];
#pragma unroll
        for (int ni = 0; ni < 4; ++ni)
            bfr[ni] = *(const bf16x8*)&Bs[(wc * 64 + ni * 16 + l15) * 32 + pxor * 8];
#pragma unroll
        for (int mi = 0; mi < 4; ++mi)
#pragma unroll
            for (int ni = 0; ni < 4; ++ni)
                acc[mi][ni] = __builtin_amdgcn_mfma_f32_16x16x32_bf16(af[mi], bfr[ni], acc[mi][ni], 0, 0, 0);
        __syncthreads();          // all reads done before next staging writes
        if (ks < 31) stage((ks + 1) * 32);
    }

    // ---- epilogue: masked d2, row-min & col-min -> atomicMin ----
    const int rb = i0 + wr * 64, cb = j0 + wc * 64;
    float sqj[4]; int lbj[4]; float cmn[4];
#pragma unroll
    for (int ni = 0; ni < 4; ++ni) {
        int cg = cb + ni * 16 + l15;
        sqj[ni] = sq[cg]; lbj[ni] = label[cg]; cmn[ni] = POSI;
    }
#pragma unroll
    for (int mi = 0; mi < 4; ++mi) {
        float rm[4] = {POSI, POSI, POSI, POSI};
        float sqi[4]; int lbi[4];
#pragma unroll
        for (int rr = 0; rr < 4; ++rr) {
            int rg = rb + mi * 16 + q * 4 + rr;
            sqi[rr] = sq[rg]; lbi[rr] = label[rg];
        }
#pragma unroll
        for (int ni = 0; ni < 4; ++ni)
#pragma unroll
            for (int rr = 0; rr < 4; ++rr) {
                float d2 = fmaf(-2.0f, acc[mi][ni][rr], sqi[rr] + sqj[ni]);
                d2 = fmaxf(d2, 1e-12f);
                float dn = (lbi[rr] == lbj[ni]) ? POSI : d2;
                rm[rr] = fminf(rm[rr], dn);
                cmn[ni] = fminf(cmn[ni], dn);
            }
#pragma unroll
        for (int rr = 0; rr < 4; ++rr) {
            float v = rm[rr];
            v = fminf(v, __shfl_xor(v, 1));
            v = fminf(v, __shfl_xor(v, 2));
            v = fminf(v, __shfl_xor(v, 4));
            v = fminf(v, __shfl_xor(v, 8));
            if (l15 == 0) atomicMin(&mnA[rb + mi * 16 + q * 4 + rr], __float_as_uint(v));
        }
    }
#pragma unroll
    for (int ni = 0; ni < 4; ++ni) {
        float v = cmn[ni];
        v = fminf(v, __shfl_xor(v, 16));
        v = fminf(v, __shfl_xor(v, 32));
        if (q == 0) atomicMin(&mnA[cb + ni * 16 + l15], __float_as_uint(v));
    }
}

// ---------------- K5: per-CLASS positives (top-2) + alphas ----------------
// ROUND-6 DELTA: one block per class (512 blocks). Stage the class's <=CAPR member rows
// once into LDS (96KB), then all-pairs d2 in-LDS: removes the ~270MB of per-row classmate
// re-reads. d2 / self (d2=1e-12) / tie-break (lower GLOBAL index) / cc==1 fallback logic
// is byte-identical to the previously passing per-row version. Members beyond CAPR (never
// for this input) read from global via generic pointers -- correctness for any distribution.
__global__ __launch_bounds__(256) void k_pos(const short* __restrict__ embb,
                                             const float* __restrict__ sq,
                                             const float* __restrict__ clot,
                                             const int* __restrict__ label,
                                             const int* __restrict__ cnt,
                                             const int* __restrict__ clsOff,
                                             const int* __restrict__ clsList,
                                             const unsigned* __restrict__ mnA,
                                             float* __restrict__ ap1, float* __restrict__ ap2,
                                             float* __restrict__ an,
                                             float* __restrict__ alpha1, float* __restrict__ alpha2) {
    const int cls = blockIdx.x;
    const int cc = cnt[cls], off = clsOff[cls];
    if (cc == 0) return;                      // uniform per block: no barrier divergence

    __shared__ __align__(16) short Ls[CAPR * DE];   // 96KB
    __shared__ int gidS[256];
    __shared__ float sqS[256];

    const int tid = threadIdx.x, wid = tid >> 6, lane = tid & 63;
    const int ccap = cc < 256 ? cc : 256;
    for (int m = tid; m < ccap; m += 256) {
        int gid = clsList[off + m];
        gidS[m] = gid;
        sqS[m] = sq[gid];
    }
    __syncthreads();
    const int nst = cc < CAPR ? cc : CAPR;
    for (int idx = tid; idx < nst * 128; idx += 256) {
        int m = idx >> 7, ch = idx & 127;
        *(int4*)&Ls[m * DE + ch * 8] = *(const int4*)&embb[(size_t)gidS[m] * DE + ch * 8];
    }
    __syncthreads();

    for (int m = wid; m < cc; m += 4) {
        const int gm = (m < 256) ? gidS[m] : clsList[off + m];
        const float sqm = (m < 256) ? sqS[m] : sq[gm];
        const short* mrow = (m < CAPR) ? (const short*)&Ls[m * DE] : &embb[(size_t)gm * DE];
        bf16x8 ra = *(const bf16x8*)&mrow[lane * 16];
        bf16x8 rbv = *(const bf16x8*)&mrow[lane * 16 + 8];
        float rf[16];
#pragma unroll
        for (int t = 0; t < 8; ++t) { rf[t] = b2f(ra[t]); rf[8 + t] = b2f(rbv[t]); }

        float v1 = NEGI, v2 = NEGI;
        int i1 = 0, i2 = 0;
        for (int jm = 0; jm < cc; ++jm) {
            const int gj = (jm < 256) ? gidS[jm] : clsList[off + jm];
            float d2;
            if (jm == m) {
                d2 = 1e-12f;
            } else {
                const short* jrow = (jm < CAPR) ? (const short*)&Ls[jm * DE] : &embb[(size_t)gj * DE];
                bf16x8 ja = *(const bf16x8*)&jrow[lane * 16];
                bf16x8 jb = *(const bf16x8*)&jrow[lane * 16 + 8];
                float s = 0.f;
#pragma unroll
                for (int t = 0; t < 8; ++t) s = fmaf(rf[t], b2f(ja[t]), s);
#pragma unroll
                for (int t = 0; t < 8; ++t) s = fmaf(rf[8 + t], b2f(jb[t]), s);
                for (int mm = 1; mm < 64; mm <<= 1) s += __shfl_xor(s, mm);
                const float sqj = (jm < 256) ? sqS[jm] : sq[gj];
                d2 = fmaxf(fmaf(-2.0f, s, sqm + sqj), 1e-12f);
            }
            bool t1 = (d2 > v1) || (d2 == v1 && gj < i1);
            bool t2 = (d2 > v2) || (d2 == v2 && gj < i2);
            v2 = t1 ? v1 : (t2 ? d2 : v2);
            i2 = t1 ? i1 : (t2 ? gj : i2);
            v1 = t1 ? d2 : v1;
            i1 = t1 ? gj : i1;
        }

        float a1 = sqrtf(v1);
        int j1 = i1;
        float a2v; int j2;
        if (cc >= 2) {
            a2v = sqrtf(v2);
            j2 = i2;
        } else {
            // singleton class: ref falls back to best (max-dist) negative - BIG
            float kv = NEGI; int ki = 0;
            for (int cr = lane; cr < NR; cr += 64) {
                if (label[cr] == cls) continue;
                float s = 0.f;
                const short* crow = embb + (size_t)cr * DE;
                const short* rrow = embb + (size_t)gm * DE;
                for (int t = 0; t < DE; ++t) s = fmaf(b2f(rrow[t]), b2f(crow[t]), s);
                float d2c = fmaxf(fmaf(-2.0f, s, sqm + sq[cr]), 1e-12f);
                bool tk = (d2c > kv) || (d2c == kv && cr < ki);
                kv = tk ? d2c : kv; ki = tk ? cr : ki;
            }
            for (int mm = 1; mm < 64; mm <<= 1) {
                float ov = __shfl_xor(kv, mm); int oi = __shfl_xor(ki, mm);
                bool tk = (ov > kv) || (ov == kv && oi < ki);
                kv = tk ? ov : kv; ki = tk ? oi : ki;
            }
            a2v = sqrtf(kv) - BIGF;
            j2 = ki;
        }

        // alpha dots + norms over clot (global; small & cache-hot)
        const float4* c4 = (const float4*)clot;
        float s1 = 0.f, s2 = 0.f, n0 = 0.f, n1 = 0.f, n2 = 0.f;
        for (int t = lane; t < DC / 4; t += 64) {
            float4 a = c4[(size_t)gm * (DC / 4) + t];
            float4 b1 = c4[(size_t)j1 * (DC / 4) + t];
            float4 b2 = c4[(size_t)j2 * (DC / 4) + t];
            s1 += a.x * b1.x + a.y * b1.y + a.z * b1.z + a.w * b1.w;
            s2 += a.x * b2.x + a.y * b2.y + a.z * b2.z + a.w * b2.w;
            n0 += a.x * a.x + a.y * a.y + a.z * a.z + a.w * a.w;
            n1 += b1.x * b1.x + b1.y * b1.y + b1.z * b1.z + b1.w * b1.w;
            n2 += b2.x * b2.x + b2.y * b2.y + b2.z * b2.z + b2.w * b2.w;
        }
        for (int mm = 1; mm < 64; mm <<= 1) {
            s1 += __shfl_xor(s1, mm); s2 += __shfl_xor(s2, mm);
            n0 += __shfl_xor(n0, mm); n1 += __shfl_xor(n1, mm); n2 += __shfl_xor(n2, mm);
        }
        if (lane == 0) {
            ap1[gm] = a1; ap2[gm] = a2v;
            an[gm] = sqrtf(__uint_as_float(mnA[gm]));
            alpha1[gm] = s1 / (sqrtf(n0) * sqrtf(n1));
            alpha2[gm] = s2 / (sqrtf(n0) * sqrtf(n2));
        }
    }
}

// ---------------- K7: final loss + prec ----------------
__global__ __launch_bounds__(256) void k_final(const float* __restrict__ ap1, const float* __restrict__ ap2,
                                               const float* __restrict__ an,
                                               const float* __restrict__ alpha1, const float* __restrict__ alpha2,
                                               float* __restrict__ out) {
    int tid = threadIdx.x;
    float sl11 = 0.f, sl13 = 0.f, sp = 0.f;
    for (int row = tid; row < NR; row += 256) {
        float a1 = alpha1[row], a2 = alpha2[row];
        float dap1 = ap1[row], dap2 = ap2[row], dan = an[row];
        float y = (a1 < a2) ? -1.f : 1.f;
        float ym = (a1 == a2) ? 0.f : 1.f;
        float x1 = dap2 * ym;
        float x2 = dap1 * ym + MARG * (a1 - a2 - y);
        sl11 += fmaxf(0.f, -y * (x1 - x2) + MARG);
        float ap1m = dap1 + MARG * (a1 - 1.f);
        sl13 += fmaxf(0.f, -(dan - ap1m) + MARG);
        sp += (dan > ap1m) ? 1.f : 0.f;
    }
    for (int m = 1; m < 64; m <<= 1) {
        sl11 += __shfl_xor(sl11, m);
        sl13 += __shfl_xor(sl13, m);
        sp += __shfl_xor(sp, m);
    }
    __shared__ float r11[4], r13[4], rp[4];
    if ((tid & 63) == 0) { r11[tid >> 6] = sl11; r13[tid >> 6] = sl13; rp[tid >> 6] = sp; }
    __syncthreads();
    if (tid == 0) {
        float t11 = r11[0] + r11[1] + r11[2] + r11[3];
        float t13 = r13[0] + r13[1] + r13[2] + r13[3];
        float tp = rp[0] + rp[1] + rp[2] + rp[3];
        out[0] = 0.1f * (t11 / (float)NR) + t13 / (float)NR;
        out[1] = tp / (float)NR;
    }
}

extern "C" void kernel_launch(void* const* d_in, const int* in_sizes, int n_in,
                              void* d_out, int out_size, void* d_ws, size_t ws_size,
                              hipStream_t stream) {
    const float* emb = (const float*)d_in[0];
    const int* label = (const int*)d_in[1];
    const float* clot = (const float*)d_in[2];
    float* out = (float*)d_out;

    char* ws = (char*)d_ws;
    size_t off = 0;
    auto alloc = [&](size_t bytes) -> char* {
        char* p = ws + off;
        off = (off + bytes + 255) & ~(size_t)255;
        return p;
    };
    short*    embb = (short*)alloc((size_t)NR * DE * 2);
    float*    sq   = (float*)alloc(NR * 4);
    int*      cnt  = (int*)alloc(512 * 4);
    int*      cOff = (int*)alloc(512 * 4);
    int*      fill = (int*)alloc(512 * 4);
    int*      list = (int*)alloc(NR * 4);
    unsigned* mnA  = (unsigned*)alloc((size_t)NR * 4);
    float*    ap1  = (float*)alloc(NR * 4);
    float*    ap2  = (float*)alloc(NR * 4);
    float*    an   = (float*)alloc(NR * 4);
    float*    al1  = (float*)alloc(NR * 4);
    float*    al2  = (float*)alloc(NR * 4);

    hipMemsetAsync(cnt, 0, 512 * 4, stream);
    hipMemsetAsync(fill, 0, 512 * 4, stream);
    hipMemsetAsync(mnA, 0xFF, (size_t)NR * 4, stream);   // large bits: +inf for positive-float min

    k_prep_emb<<<dim3(NR), dim3(256), 0, stream>>>(emb, label, embb, sq, cnt);
    k_scan<<<dim3(1), dim3(512), 0, stream>>>(cnt, cOff);
    k_fill<<<dim3(NR / 256), dim3(256), 0, stream>>>(label, cOff, fill, list);
    k_main<<<dim3(2080), dim3(256), 0, stream>>>(embb, sq, label, mnA);
    k_pos<<<dim3(512), dim3(256), 0, stream>>>(embb, sq, clot, label, cnt, cOff, list,
                                               mnA, ap1, ap2, an, al1, al2);
    k_final<<<dim3(1), dim3(256), 0, stream>>>(ap1, ap2, an, al1, al2, out);
}

// Round 7
// 241.813 us; speedup vs baseline: 1.5766x; 1.5766x over previous
//
#include <hip/hip_runtime.h>
#include <stdint.h>

#define NR 8192
#define DE 1024
#define DC 512
#define BIGF 9999999.0f
#define MARG 0.3f
#define NEGI -3.0e38f
#define POSI 3.0e38f

typedef __attribute__((ext_vector_type(8))) short bf16x8;
typedef __attribute__((ext_vector_type(4))) float f32x4;

typedef __attribute__((address_space(3))) unsigned int lds_u32;
typedef const __attribute__((address_space(1))) unsigned int glb_u32;

static __device__ __forceinline__ void ld_g2l16(const void* g, void* l) {
    __builtin_amdgcn_global_load_lds((glb_u32*)g, (lds_u32*)l, 16, 0, 0);
}

static __device__ __forceinline__ unsigned short f2bf(float x) {
    unsigned u = __float_as_uint(x);
    unsigned r = u + 0x7FFFu + ((u >> 16) & 1u);
    return (unsigned short)(r >> 16);
}

static __device__ __forceinline__ float b2f(short u) {
    return __uint_as_float(((unsigned)(unsigned short)u) << 16);
}

// ---------------- K1: emb -> bf16, sq[i] = ||emb_i||^2, class histogram ----------------
__global__ __launch_bounds__(256) void k_prep_emb(const float* __restrict__ emb,
                                                  const int* __restrict__ label,
                                                  short* __restrict__ embb,
                                                  float* __restrict__ sq,
                                                  int* __restrict__ cnt) {
    int row = blockIdx.x, tid = threadIdx.x;
    float4 v = ((const float4*)(emb + (size_t)row * DE))[tid];
    float s = v.x * v.x + v.y * v.y + v.z * v.z + v.w * v.w;
    ushort4 b;
    b.x = f2bf(v.x); b.y = f2bf(v.y); b.z = f2bf(v.z); b.w = f2bf(v.w);
    *(ushort4*)&embb[(size_t)row * DE + tid * 4] = b;
    for (int m = 1; m < 64; m <<= 1) s += __shfl_xor(s, m);
    __shared__ float red[4];
    if ((tid & 63) == 0) red[tid >> 6] = s;
    __syncthreads();
    if (tid == 0) {
        sq[row] = red[0] + red[1] + red[2] + red[3];
        atomicAdd(&cnt[label[row]], 1);
    }
}

// ---------------- K2: exclusive scan of class counts (512, single block) ----------------
__global__ __launch_bounds__(512) void k_scan(const int* __restrict__ cnt,
                                              int* __restrict__ clsOff) {
    __shared__ int s[512];
    int t = threadIdx.x;
    s[t] = cnt[t];
    __syncthreads();
    for (int d = 1; d < 512; d <<= 1) {
        int v = (t >= d) ? s[t - d] : 0;
        __syncthreads();
        s[t] += v;
        __syncthreads();
    }
    clsOff[t] = s[t] - cnt[t];
}

// ---------------- K3: scatter rows into class member lists ----------------
__global__ __launch_bounds__(256) void k_fill(const int* __restrict__ label,
                                              const int* __restrict__ clsOff,
                                              int* __restrict__ fill,
                                              int* __restrict__ list) {
    int i = blockIdx.x * 256 + threadIdx.x;
    int l = label[i];
    int p = atomicAdd(&fill[l], 1);
    list[clsOff[l] + p] = i;
}

// ---------------- K4: symmetric GEMM + min-of-negative row & column reductions ----------------
// Per-PANEL grid (unchanged from round 6 -- this is the ONLY live experiment this round):
//  - 2080 blocks, one 128x128 upper-tri panel each (r<=c<64), 32 K-steps; dynamic refill
//    fixes the 544-block residency imbalance (544 = 2*256+32 -> 32 CUs carried 1.48x work).
//  - 2x2 wave arrangement, 64x64 per wave (acc[4][4]): B-read duplication 4x->2x,
//    LDS/K-step 56->48KB.
//  - proven round-0 skeleton otherwise: 2-barrier K-step, gload_lds staging + source
//    swizzle, pxor fragment swizzle, 16KB LDS, launch_bounds(256,3).
__global__ __launch_bounds__(256, 3) void k_main(const short* __restrict__ embb,
                                                 const float* __restrict__ sq,
                                                 const int* __restrict__ label,
                                                 unsigned* __restrict__ mnA) {
    // decode b -> (r, c), r <= c < 64: off(r) = 64r - r(r-1)/2 ; c = r + (b - off(r))
    const int b = blockIdx.x;
    int r = (int)((129.0f - sqrtf(16641.0f - 8.0f * (float)b)) * 0.5f);
    if (r < 0) r = 0;
    if (r > 63) r = 63;
    while (r > 0 && 64 * r - (r * (r - 1)) / 2 > b) --r;
    while (64 * (r + 1) - ((r + 1) * r) / 2 <= b) ++r;
    const int c = r + (b - (64 * r - (r * (r - 1)) / 2));
    const int i0 = r * 128, j0 = c * 128;

    __shared__ __align__(16) short As[128 * 32];
    __shared__ __align__(16) short Bs[128 * 32];

    const int tid = threadIdx.x;
    const int lane = tid & 63;
    const int w = tid >> 6;
    const int wr = w >> 1, wc = w & 1;       // 2x2 wave grid over the 128x128 panel
    const int q = lane >> 4, l15 = lane & 15;

    // staging source swizzle: slot rr = tid>>2, c = tid&3 -> global chunk g (verbatim R0)
    const int srow = tid >> 2;
    const int g = (tid & 3) ^ ((tid >> 3) & 3);
    const short* gA = embb + (size_t)(i0 + srow) * DE + g * 8;
    const short* gB = embb + (size_t)(j0 + srow) * DE + g * 8;

    // fragment read swizzle (conflict-free; valid for any 16-aligned row base)
    const int pxor = q ^ ((l15 >> 1) & 3);

    auto stage = [&](int koff) {
        ld_g2l16(gA + koff, &As[(size_t)tid * 8]);
        ld_g2l16(gA + (size_t)64 * DE + koff, &As[(size_t)(tid + 256) * 8]);
        ld_g2l16(gB + koff, &Bs[(size_t)tid * 8]);
        ld_g2l16(gB + (size_t)64 * DE + koff, &Bs[(size_t)(tid + 256) * 8]);
    };

    stage(0);   // prefetch ks=0

    f32x4 acc[4][4];
#pragma unroll
    for (int mi = 0; mi < 4; ++mi)
#pragma unroll
        for (int ni = 0; ni < 4; ++ni) acc[mi][ni] = (f32x4){0.f, 0.f, 0.f, 0.f};

    for (int ks = 0; ks < 32; ++ks) {
        __syncthreads();          // staging visible (vmcnt drain)
        bf16x8 af[4], bfr[4];
#pragma unroll
        for (int mi = 0; mi < 4; ++mi)
            af[mi] = *(const bf16x8*)&As[(wr * 64 + mi * 16 + l15) * 32 + pxor * 8];
#pragma unroll
        for (int ni = 0; ni < 4; ++ni)
            bfr[ni] = *(const bf16x8*)&Bs[(wc * 64 + ni * 16 + l15) * 32 + pxor * 8];
#pragma unroll
        for (int mi = 0; mi < 4; ++mi)
#pragma unroll
            for (int ni = 0; ni < 4; ++ni)
                acc[mi][ni] = __builtin_amdgcn_mfma_f32_16x16x32_bf16(af[mi], bfr[ni], acc[mi][ni], 0, 0, 0);
        __syncthreads();          // all reads done before next staging writes
        if (ks < 31) stage((ks + 1) * 32);
    }

    // ---- epilogue: masked d2, row-min & col-min -> atomicMin ----
    const int rb = i0 + wr * 64, cb = j0 + wc * 64;
    float sqj[4]; int lbj[4]; float cmn[4];
#pragma unroll
    for (int ni = 0; ni < 4; ++ni) {
        int cg = cb + ni * 16 + l15;
        sqj[ni] = sq[cg]; lbj[ni] = label[cg]; cmn[ni] = POSI;
    }
#pragma unroll
    for (int mi = 0; mi < 4; ++mi) {
        float rm[4] = {POSI, POSI, POSI, POSI};
        float sqi[4]; int lbi[4];
#pragma unroll
        for (int rr = 0; rr < 4; ++rr) {
            int rg = rb + mi * 16 + q * 4 + rr;
            sqi[rr] = sq[rg]; lbi[rr] = label[rg];
        }
#pragma unroll
        for (int ni = 0; ni < 4; ++ni)
#pragma unroll
            for (int rr = 0; rr < 4; ++rr) {
                float d2 = fmaf(-2.0f, acc[mi][ni][rr], sqi[rr] + sqj[ni]);
                d2 = fmaxf(d2, 1e-12f);
                float dn = (lbi[rr] == lbj[ni]) ? POSI : d2;
                rm[rr] = fminf(rm[rr], dn);
                cmn[ni] = fminf(cmn[ni], dn);
            }
#pragma unroll
        for (int rr = 0; rr < 4; ++rr) {
            float v = rm[rr];
            v = fminf(v, __shfl_xor(v, 1));
            v = fminf(v, __shfl_xor(v, 2));
            v = fminf(v, __shfl_xor(v, 4));
            v = fminf(v, __shfl_xor(v, 8));
            if (l15 == 0) atomicMin(&mnA[rb + mi * 16 + q * 4 + rr], __float_as_uint(v));
        }
    }
#pragma unroll
    for (int ni = 0; ni < 4; ++ni) {
        float v = cmn[ni];
        v = fminf(v, __shfl_xor(v, 16));
        v = fminf(v, __shfl_xor(v, 32));
        if (q == 0) atomicMin(&mnA[cb + ni * 16 + l15], __float_as_uint(v));
    }
}

// ---------------- K5: exact per-row positives (top-2 over classmates) + alphas ----------------
// REVERTED byte-for-byte to the round-0 version (proven within the 249.5us baseline).
// The round-6 per-class LDS rewrite measured 182us (occupancy 5.5%, 1.1M bank conflicts,
// latency-bound on a 512-block grid) -- strictly worse; classmate rows are L3-resident
// anyway, so LDS staging bought nothing and destroyed parallelism.
__global__ __launch_bounds__(256) void k_pos(const short* __restrict__ embb,
                                             const float* __restrict__ sq,
                                             const float* __restrict__ clot,
                                             const int* __restrict__ label,
                                             const int* __restrict__ cnt,
                                             const int* __restrict__ clsOff,
                                             const int* __restrict__ clsList,
                                             const unsigned* __restrict__ mnA,
                                             float* __restrict__ ap1, float* __restrict__ ap2,
                                             float* __restrict__ an,
                                             float* __restrict__ alpha1, float* __restrict__ alpha2) {
    int wid = threadIdx.x >> 6, lane = threadIdx.x & 63;
    int row = blockIdx.x * 4 + wid;
    int lb = label[row];
    int cc = cnt[lb], off = clsOff[lb];
    float sqiv = sq[row];

    // row chunk: lane covers dims [lane*16, lane*16+16)
    const bf16x8* rp = (const bf16x8*)(embb + (size_t)row * DE + lane * 16);
    bf16x8 ra = rp[0], rb = rp[1];
    float rf[16];
#pragma unroll
    for (int t = 0; t < 8; ++t) { rf[t] = b2f(ra[t]); rf[8 + t] = b2f(rb[t]); }

    float v1 = NEGI, v2 = NEGI;
    int i1 = 0, i2 = 0;
    for (int m = 0; m < cc; ++m) {
        int j = clsList[off + m];
        float d2;
        if (j == row) {
            d2 = 1e-12f;
        } else {
            const bf16x8* jp = (const bf16x8*)(embb + (size_t)j * DE + lane * 16);
            bf16x8 ja = jp[0], jb = jp[1];
            float s = 0.f;
#pragma unroll
            for (int t = 0; t < 8; ++t) s = fmaf(rf[t], b2f(ja[t]), s);
#pragma unroll
            for (int t = 0; t < 8; ++t) s = fmaf(rf[8 + t], b2f(jb[t]), s);
            for (int mm = 1; mm < 64; mm <<= 1) s += __shfl_xor(s, mm);
            d2 = fmaxf(fmaf(-2.0f, s, sqiv + sq[j]), 1e-12f);
        }
        bool t1 = (d2 > v1) || (d2 == v1 && j < i1);
        bool t2 = (d2 > v2) || (d2 == v2 && j < i2);
        v2 = t1 ? v1 : (t2 ? d2 : v2);
        i2 = t1 ? i1 : (t2 ? j : i2);
        v1 = t1 ? d2 : v1;
        i1 = t1 ? j : i1;
    }

    float a1 = sqrtf(v1);
    int j1 = i1;
    float a2v; int j2;
    if (cc >= 2) {
        a2v = sqrtf(v2);
        j2 = i2;
    } else {
        // singleton class: ref falls back to best (max-dist) negative - BIG
        float kv = NEGI; int ki = 0;
        for (int c = lane; c < NR; c += 64) {
            if (label[c] == lb) continue;
            float s = 0.f;
            const short* crow = embb + (size_t)c * DE;
            const short* rrow = embb + (size_t)row * DE;
            for (int t = 0; t < DE; ++t) s = fmaf(b2f(rrow[t]), b2f(crow[t]), s);
            float d2c = fmaxf(fmaf(-2.0f, s, sqiv + sq[c]), 1e-12f);
            bool tk = (d2c > kv) || (d2c == kv && c < ki);
            kv = tk ? d2c : kv; ki = tk ? c : ki;
        }
        for (int mm = 1; mm < 64; mm <<= 1) {
            float ov = __shfl_xor(kv, mm); int oi = __shfl_xor(ki, mm);
            bool tk = (ov > kv) || (ov == kv && oi < ki);
            kv = tk ? ov : kv; ki = tk ? oi : ki;
        }
        a2v = sqrtf(kv) - BIGF;
        j2 = ki;
    }

    // alpha dots + norms over clot
    const float4* c4 = (const float4*)clot;
    float s1 = 0.f, s2 = 0.f, n0 = 0.f, n1 = 0.f, n2 = 0.f;
    for (int t = lane; t < DC / 4; t += 64) {
        float4 a = c4[(size_t)row * (DC / 4) + t];
        float4 b1 = c4[(size_t)j1 * (DC / 4) + t];
        float4 b2 = c4[(size_t)j2 * (DC / 4) + t];
        s1 += a.x * b1.x + a.y * b1.y + a.z * b1.z + a.w * b1.w;
        s2 += a.x * b2.x + a.y * b2.y + a.z * b2.z + a.w * b2.w;
        n0 += a.x * a.x + a.y * a.y + a.z * a.z + a.w * a.w;
        n1 += b1.x * b1.x + b1.y * b1.y + b1.z * b1.z + b1.w * b1.w;
        n2 += b2.x * b2.x + b2.y * b2.y + b2.z * b2.z + b2.w * b2.w;
    }
    for (int mm = 1; mm < 64; mm <<= 1) {
        s1 += __shfl_xor(s1, mm); s2 += __shfl_xor(s2, mm);
        n0 += __shfl_xor(n0, mm); n1 += __shfl_xor(n1, mm); n2 += __shfl_xor(n2, mm);
    }
    if (lane == 0) {
        ap1[row] = a1; ap2[row] = a2v;
        an[row] = sqrtf(__uint_as_float(mnA[row]));
        alpha1[row] = s1 / (sqrtf(n0) * sqrtf(n1));
        alpha2[row] = s2 / (sqrtf(n0) * sqrtf(n2));
    }
}

// ---------------- K7: final loss + prec ----------------
__global__ __launch_bounds__(256) void k_final(const float* __restrict__ ap1, const float* __restrict__ ap2,
                                               const float* __restrict__ an,
                                               const float* __restrict__ alpha1, const float* __restrict__ alpha2,
                                               float* __restrict__ out) {
    int tid = threadIdx.x;
    float sl11 = 0.f, sl13 = 0.f, sp = 0.f;
    for (int row = tid; row < NR; row += 256) {
        float a1 = alpha1[row], a2 = alpha2[row];
        float dap1 = ap1[row], dap2 = ap2[row], dan = an[row];
        float y = (a1 < a2) ? -1.f : 1.f;
        float ym = (a1 == a2) ? 0.f : 1.f;
        float x1 = dap2 * ym;
        float x2 = dap1 * ym + MARG * (a1 - a2 - y);
        sl11 += fmaxf(0.f, -y * (x1 - x2) + MARG);
        float ap1m = dap1 + MARG * (a1 - 1.f);
        sl13 += fmaxf(0.f, -(dan - ap1m) + MARG);
        sp += (dan > ap1m) ? 1.f : 0.f;
    }
    for (int m = 1; m < 64; m <<= 1) {
        sl11 += __shfl_xor(sl11, m);
        sl13 += __shfl_xor(sl13, m);
        sp += __shfl_xor(sp, m);
    }
    __shared__ float r11[4], r13[4], rp[4];
    if ((tid & 63) == 0) { r11[tid >> 6] = sl11; r13[tid >> 6] = sl13; rp[tid >> 6] = sp; }
    __syncthreads();
    if (tid == 0) {
        float t11 = r11[0] + r11[1] + r11[2] + r11[3];
        float t13 = r13[0] + r13[1] + r13[2] + r13[3];
        float tp = rp[0] + rp[1] + rp[2] + rp[3];
        out[0] = 0.1f * (t11 / (float)NR) + t13 / (float)NR;
        out[1] = tp / (float)NR;
    }
}

extern "C" void kernel_launch(void* const* d_in, const int* in_sizes, int n_in,
                              void* d_out, int out_size, void* d_ws, size_t ws_size,
                              hipStream_t stream) {
    const float* emb = (const float*)d_in[0];
    const int* label = (const int*)d_in[1];
    const float* clot = (const float*)d_in[2];
    float* out = (float*)d_out;

    char* ws = (char*)d_ws;
    size_t off = 0;
    auto alloc = [&](size_t bytes) -> char* {
        char* p = ws + off;
        off = (off + bytes + 255) & ~(size_t)255;
        return p;
    };
    short*    embb = (short*)alloc((size_t)NR * DE * 2);
    float*    sq   = (float*)alloc(NR * 4);
    int*      cnt  = (int*)alloc(512 * 4);
    int*      cOff = (int*)alloc(512 * 4);
    int*      fill = (int*)alloc(512 * 4);
    int*      list = (int*)alloc(NR * 4);
    unsigned* mnA  = (unsigned*)alloc((size_t)NR * 4);
    float*    ap1  = (float*)alloc(NR * 4);
    float*    ap2  = (float*)alloc(NR * 4);
    float*    an   = (float*)alloc(NR * 4);
    float*    al1  = (float*)alloc(NR * 4);
    float*    al2  = (float*)alloc(NR * 4);

    hipMemsetAsync(cnt, 0, 512 * 4, stream);
    hipMemsetAsync(fill, 0, 512 * 4, stream);
    hipMemsetAsync(mnA, 0xFF, (size_t)NR * 4, stream);   // large bits: +inf for positive-float min

    k_prep_emb<<<dim3(NR), dim3(256), 0, stream>>>(emb, label, embb, sq, cnt);
    k_scan<<<dim3(1), dim3(512), 0, stream>>>(cnt, cOff);
    k_fill<<<dim3(NR / 256), dim3(256), 0, stream>>>(label, cOff, fill, list);
    k_main<<<dim3(2080), dim3(256), 0, stream>>>(embb, sq, label, mnA);
    k_pos<<<dim3(NR / 4), dim3(256), 0, stream>>>(embb, sq, clot, label, cnt, cOff, list,
                                                  mnA, ap1, ap2, an, al1, al2);
    k_final<<<dim3(1), dim3(256), 0, stream>>>(ap1, ap2, an, al1, al2, out);
}